// Round 6
// baseline (449.968 us; speedup 1.0000x reference)
//
#include <hip/hip_runtime.h>

#define N_NODES 50000
#define N_EDGES 800000
#define HID 128
#define SCAN_BLK 256
#define AP 133   // padded row stride for As; bank = (5*row + col) % 32

// ---------------- degrees ----------------
__global__ void deg_kernel(const int* __restrict__ src, const int* __restrict__ dst,
                           int* __restrict__ cnt_out, int* __restrict__ cnt_in) {
  int e = blockIdx.x * blockDim.x + threadIdx.x;
  if (e < N_EDGES) {
    atomicAdd(&cnt_out[src[e]], 1);
    atomicAdd(&cnt_in[dst[e]], 1);
  }
}

__global__ void norm_kernel(const int* __restrict__ cnt_out, const int* __restrict__ cnt_in,
                            float* __restrict__ norm_out, float* __restrict__ norm_in) {
  int v = blockIdx.x * blockDim.x + threadIdx.x;
  if (v < N_NODES) {
    int co = cnt_out[v]; if (co < 1) co = 1;
    int ci = cnt_in[v];  if (ci < 1) ci = 1;
    norm_out[v] = rsqrtf((float)co);
    norm_in[v]  = rsqrtf((float)ci);
  }
}

// ---------------- CSR build ----------------
__global__ void scan_blocks_kernel(const int* __restrict__ cnt, int* __restrict__ ofs,
                                   int* __restrict__ blk_sums, int n) {
  __shared__ int s[SCAN_BLK];
  int t = threadIdx.x;
  int i = blockIdx.x * SCAN_BLK + t;
  int v = (i < n) ? cnt[i] : 0;
  s[t] = v;
  __syncthreads();
  for (int o = 1; o < SCAN_BLK; o <<= 1) {
    int x = (t >= o) ? s[t - o] : 0;
    __syncthreads();
    s[t] += x;
    __syncthreads();
  }
  if (i < n) ofs[i] = s[t] - v;
  if (t == SCAN_BLK - 1) blk_sums[blockIdx.x] = s[t];
}

__global__ void scan_sums_kernel(const int* __restrict__ blk_sums, int* __restrict__ blk_base,
                                 int nb) {
  __shared__ int s[SCAN_BLK];
  int t = threadIdx.x;
  int v = (t < nb) ? blk_sums[t] : 0;
  s[t] = v;
  __syncthreads();
  for (int o = 1; o < SCAN_BLK; o <<= 1) {
    int x = (t >= o) ? s[t - o] : 0;
    __syncthreads();
    s[t] += x;
    __syncthreads();
  }
  if (t < nb) blk_base[t] = s[t] - v;
}

__global__ void add_base_kernel(int* __restrict__ ofs, const int* __restrict__ blk_base,
                                int* __restrict__ cursor, int n, int total) {
  int i = blockIdx.x * blockDim.x + threadIdx.x;
  if (i < n) {
    int r = ofs[i] + blk_base[i >> 8];
    ofs[i] = r;
    cursor[i] = r;
  }
  if (i == 0) ofs[n] = total;
}

__global__ void csr_fill_kernel(const int* __restrict__ src, const int* __restrict__ dst,
                                int* __restrict__ cursor, int* __restrict__ csr_src,
                                int* __restrict__ csr_eid) {
  int e = blockIdx.x * blockDim.x + threadIdx.x;
  if (e < N_EDGES) {
    int p = atomicAdd(&cursor[dst[e]], 1);
    csr_src[p] = src[e];
    csr_eid[p] = e;
  }
}

// ---------------- layer-1 aggregate on RAW 4-dim features ----------------
__global__ __launch_bounds__(256) void agg4_kernel(
    const float4* __restrict__ nf4, const float* __restrict__ no_,
    const int* __restrict__ csr_src, const int* __restrict__ row_ofs,
    float4* __restrict__ agg4, float* __restrict__ sno) {
  int wid = (blockIdx.x * blockDim.x + threadIdx.x) >> 6;
  int lane = threadIdx.x & 63;
  int g = lane >> 4, l = lane & 15;
  int v = wid * 4 + g;
  if (v >= N_NODES) return;
  int beg = row_ofs[v], end = row_ofs[v + 1];
  float ax = 0.f, ay = 0.f, az = 0.f, aw = 0.f, sn = 0.f;
  for (int i = beg + l; i < end; i += 16) {
    int s = csr_src[i];
    float w = no_[s];
    float4 n = nf4[s];
    ax += n.x * w; ay += n.y * w; az += n.z * w; aw += n.w * w;
    sn += w;
  }
#pragma unroll
  for (int o = 1; o < 16; o <<= 1) {
    ax += __shfl_xor(ax, o, 16);
    ay += __shfl_xor(ay, o, 16);
    az += __shfl_xor(az, o, 16);
    aw += __shfl_xor(aw, o, 16);
    sn += __shfl_xor(sn, o, 16);
  }
  if (l == 0) {
    agg4[v] = make_float4(ax, ay, az, aw);
    sno[v] = sn;
  }
}

// ---------------- layer-1: fused 4->128 expand + GEMM, register micro-tile ----------------
__global__ __launch_bounds__(256) void gemm_l1_kernel(
    const float4* __restrict__ agg4, const float* __restrict__ sno,
    const float* __restrict__ ni_, const float* __restrict__ no_,
    const float* __restrict__ Wn, const float* __restrict__ bn,
    const float* __restrict__ W0, const float* __restrict__ b0,
    float* __restrict__ out, int nrows) {
  __shared__ float At[HID * 64];      // 32 KB, k-major
  __shared__ float Wbuf[32 * HID];    // 16 KB
  int t = threadIdx.x;
  int v0 = blockIdx.x * 64;
  {
    int r = t & 63, kg = t >> 6;
    int v = v0 + r;
    float4 a = make_float4(0.f, 0.f, 0.f, 0.f);
    float sn = 0.f, nin = 0.f;
    if (v < nrows) { a = agg4[v]; sn = sno[v]; nin = ni_[v]; }
    for (int kk = 0; kk < 32; ++kk) {
      int k = kg * 32 + kk;  // wave-uniform
      float val = (a.x * Wn[k] + a.y * Wn[HID + k] + a.z * Wn[2 * HID + k] +
                   a.w * Wn[3 * HID + k] + bn[k] * sn) * nin;
      At[k * 64 + r] = val;
    }
  }
  int c0 = (t >> 4) * 8, r0 = (t & 15) * 4;
  float acc[4][8];
#pragma unroll
  for (int i = 0; i < 4; ++i)
#pragma unroll
    for (int j = 0; j < 8; ++j) acc[i][j] = 0.f;

  for (int kc = 0; kc < HID; kc += 32) {
    __syncthreads();
    {
      const float4* wsrc = (const float4*)(W0 + kc * HID);
      float4* wdst = (float4*)Wbuf;
#pragma unroll
      for (int i = 0; i < 4; ++i) wdst[i * 256 + t] = wsrc[i * 256 + t];
    }
    __syncthreads();
#pragma unroll 4
    for (int kk = 0; kk < 32; ++kk) {
      float4 av = *(const float4*)&At[(kc + kk) * 64 + r0];
      float4 w0v = *(const float4*)&Wbuf[kk * HID + c0];
      float4 w1v = *(const float4*)&Wbuf[kk * HID + c0 + 4];
      float ar[4] = {av.x, av.y, av.z, av.w};
      float wv[8] = {w0v.x, w0v.y, w0v.z, w0v.w, w1v.x, w1v.y, w1v.z, w1v.w};
#pragma unroll
      for (int i = 0; i < 4; ++i)
#pragma unroll
        for (int j = 0; j < 8; ++j) acc[i][j] += ar[i] * wv[j];
    }
  }
  float bb[8];
  {
    float4 b0v = *(const float4*)&b0[c0];
    float4 b1v = *(const float4*)&b0[c0 + 4];
    bb[0] = b0v.x; bb[1] = b0v.y; bb[2] = b0v.z; bb[3] = b0v.w;
    bb[4] = b1v.x; bb[5] = b1v.y; bb[6] = b1v.z; bb[7] = b1v.w;
  }
#pragma unroll
  for (int i = 0; i < 4; ++i) {
    int v = v0 + r0 + i;
    if (v < nrows) {
      float nov = no_[v];
      float4 o0, o1;
      o0.x = fmaxf(acc[i][0] + bb[0], 0.f) * nov;
      o0.y = fmaxf(acc[i][1] + bb[1], 0.f) * nov;
      o0.z = fmaxf(acc[i][2] + bb[2], 0.f) * nov;
      o0.w = fmaxf(acc[i][3] + bb[3], 0.f) * nov;
      o1.x = fmaxf(acc[i][4] + bb[4], 0.f) * nov;
      o1.y = fmaxf(acc[i][5] + bb[5], 0.f) * nov;
      o1.z = fmaxf(acc[i][6] + bb[6], 0.f) * nov;
      o1.w = fmaxf(acc[i][7] + bb[7], 0.f) * nov;
      *(float4*)&out[(size_t)v * HID + c0] = o0;
      *(float4*)&out[(size_t)v * HID + c0 + 4] = o1;
    }
  }
}

// ---------------- layer-2 aggregate: wave per node, 4-deep unrolled gather ----------------
__global__ __launch_bounds__(256) void aggregate_kernel(
    const float* __restrict__ h, const int* __restrict__ row_ofs,
    const int* __restrict__ csr_src, const float* __restrict__ ni_,
    float* __restrict__ agg) {
  int v = (blockIdx.x * blockDim.x + threadIdx.x) >> 6;
  int lane = threadIdx.x & 63;
  if (v >= N_NODES) return;
  int beg = row_ofs[v], end = row_ofs[v + 1];
  int g = lane >> 4, l = lane & 15;
  const float4* __restrict__ h4 = (const float4*)h;
  float a0x = 0.f, a0y = 0.f, a0z = 0.f, a0w = 0.f;
  float a1x = 0.f, a1y = 0.f, a1z = 0.f, a1w = 0.f;
  for (int i = beg; i < end; i += 16) {
    int ii[4];
    float mm[4];
    int ss[4];
#pragma unroll
    for (int u = 0; u < 4; ++u) {
      ii[u] = i + 4 * u + g;
      bool q = ii[u] < end;
      mm[u] = q ? 1.f : 0.f;
      ss[u] = csr_src[q ? ii[u] : beg];
    }
    float4 X0[4], X1[4];
#pragma unroll
    for (int u = 0; u < 4; ++u) {
      X0[u] = h4[(size_t)ss[u] * 32 + l];
      X1[u] = h4[(size_t)ss[u] * 32 + 16 + l];
    }
#pragma unroll
    for (int u = 0; u < 4; ++u) {
      a0x += X0[u].x * mm[u]; a0y += X0[u].y * mm[u];
      a0z += X0[u].z * mm[u]; a0w += X0[u].w * mm[u];
      a1x += X1[u].x * mm[u]; a1y += X1[u].y * mm[u];
      a1z += X1[u].z * mm[u]; a1w += X1[u].w * mm[u];
    }
  }
  a0x += __shfl_xor(a0x, 16, 64); a0x += __shfl_xor(a0x, 32, 64);
  a0y += __shfl_xor(a0y, 16, 64); a0y += __shfl_xor(a0y, 32, 64);
  a0z += __shfl_xor(a0z, 16, 64); a0z += __shfl_xor(a0z, 32, 64);
  a0w += __shfl_xor(a0w, 16, 64); a0w += __shfl_xor(a0w, 32, 64);
  a1x += __shfl_xor(a1x, 16, 64); a1x += __shfl_xor(a1x, 32, 64);
  a1y += __shfl_xor(a1y, 16, 64); a1y += __shfl_xor(a1y, 32, 64);
  a1z += __shfl_xor(a1z, 16, 64); a1z += __shfl_xor(a1z, 32, 64);
  a1w += __shfl_xor(a1w, 16, 64); a1w += __shfl_xor(a1w, 32, 64);
  if (g == 0) {
    float n = ni_[v];
    float4* a4 = (float4*)agg;
    a4[(size_t)v * 32 + l] = make_float4(a0x * n, a0y * n, a0z * n, a0w * n);
    a4[(size_t)v * 32 + 16 + l] = make_float4(a1x * n, a1y * n, a1z * n, a1w * n);
  }
}

// ---------------- fused layer-2 GEMM + output GEMM, register micro-tile ----------------
// rows per thread: {m, m+16, m+32, m+48}, m=t&15  -> As bank = (5m+16i+k)%32,
// 5m distinct mod 32 for all 16 m => conflict-free scalar As reads.
__global__ __launch_bounds__(256) void gemm_dual_kernel(
    const float* __restrict__ in, const float* __restrict__ W0,
    const float* __restrict__ b0, const float* __restrict__ W1,
    float* __restrict__ out, int nrows) {
  __shared__ float As[64 * AP];
  __shared__ float Wbuf[32 * HID];
  int t = threadIdx.x;
  int v0 = blockIdx.x * 64;
  {
    const float4* in4 = (const float4*)in;
#pragma unroll
    for (int i = 0; i < 8; ++i) {
      int idx = i * 256 + t;
      int r = idx >> 5, q = idx & 31;
      int v = v0 + r;
      float4 val = make_float4(0.f, 0.f, 0.f, 0.f);
      if (v < nrows) val = in4[(size_t)v * 32 + q];
      float* p = &As[r * AP + q * 4];
      p[0] = val.x; p[1] = val.y; p[2] = val.z; p[3] = val.w;
    }
  }
  int c0 = (t >> 4) * 8, m = t & 15;
  float acc[4][8];
#pragma unroll
  for (int i = 0; i < 4; ++i)
#pragma unroll
    for (int j = 0; j < 8; ++j) acc[i][j] = 0.f;

  for (int kc = 0; kc < HID; kc += 32) {
    __syncthreads();
    {
      const float4* wsrc = (const float4*)(W0 + kc * HID);
      float4* wdst = (float4*)Wbuf;
#pragma unroll
      for (int i = 0; i < 4; ++i) wdst[i * 256 + t] = wsrc[i * 256 + t];
    }
    __syncthreads();
#pragma unroll 4
    for (int kk = 0; kk < 32; ++kk) {
      int k = kc + kk;
      float ar[4];
#pragma unroll
      for (int i = 0; i < 4; ++i) ar[i] = As[(m + 16 * i) * AP + k];
      float4 w0v = *(const float4*)&Wbuf[kk * HID + c0];
      float4 w1v = *(const float4*)&Wbuf[kk * HID + c0 + 4];
      float wv[8] = {w0v.x, w0v.y, w0v.z, w0v.w, w1v.x, w1v.y, w1v.z, w1v.w};
#pragma unroll
      for (int i = 0; i < 4; ++i)
#pragma unroll
        for (int j = 0; j < 8; ++j) acc[i][j] += ar[i] * wv[j];
    }
  }
  __syncthreads();
  {
    float bb[8];
    float4 b0v = *(const float4*)&b0[c0];
    float4 b1v = *(const float4*)&b0[c0 + 4];
    bb[0] = b0v.x; bb[1] = b0v.y; bb[2] = b0v.z; bb[3] = b0v.w;
    bb[4] = b1v.x; bb[5] = b1v.y; bb[6] = b1v.z; bb[7] = b1v.w;
#pragma unroll
    for (int i = 0; i < 4; ++i)
#pragma unroll
      for (int j = 0; j < 8; ++j) {
        As[(m + 16 * i) * AP + c0 + j] = fmaxf(acc[i][j] + bb[j], 0.f);
        acc[i][j] = 0.f;
      }
  }
  for (int kc = 0; kc < HID; kc += 32) {
    __syncthreads();
    {
      const float4* wsrc = (const float4*)(W1 + kc * HID);
      float4* wdst = (float4*)Wbuf;
#pragma unroll
      for (int i = 0; i < 4; ++i) wdst[i * 256 + t] = wsrc[i * 256 + t];
    }
    __syncthreads();
#pragma unroll 4
    for (int kk = 0; kk < 32; ++kk) {
      int k = kc + kk;
      float ar[4];
#pragma unroll
      for (int i = 0; i < 4; ++i) ar[i] = As[(m + 16 * i) * AP + k];
      float4 w0v = *(const float4*)&Wbuf[kk * HID + c0];
      float4 w1v = *(const float4*)&Wbuf[kk * HID + c0 + 4];
      float wv[8] = {w0v.x, w0v.y, w0v.z, w0v.w, w1v.x, w1v.y, w1v.z, w1v.w};
#pragma unroll
      for (int i = 0; i < 4; ++i)
#pragma unroll
        for (int j = 0; j < 8; ++j) acc[i][j] += ar[i] * wv[j];
    }
  }
#pragma unroll
  for (int i = 0; i < 4; ++i) {
    int v = v0 + m + 16 * i;
    if (v < nrows) {
      float4 o0 = make_float4(acc[i][0], acc[i][1], acc[i][2], acc[i][3]);
      float4 o1 = make_float4(acc[i][4], acc[i][5], acc[i][6], acc[i][7]);
      *(float4*)&out[(size_t)v * HID + c0] = o0;
      *(float4*)&out[(size_t)v * HID + c0 + 4] = o1;
    }
  }
}

// ---------------- edge output, dst-grouped, 16 lanes/edge, 4-deep unroll ----------------
__global__ __launch_bounds__(256) void edge_out_kernel(
    const int* __restrict__ csr_src, const int* __restrict__ csr_eid,
    const int* __restrict__ row_ofs, const float* __restrict__ y,
    const float* __restrict__ b1, const float* __restrict__ w2,
    const float* __restrict__ b2, float* __restrict__ out) {
  int v = (blockIdx.x * blockDim.x + threadIdx.x) >> 6;
  int lane = threadIdx.x & 63;
  if (v >= N_NODES) return;
  int beg = row_ofs[v], end = row_ofs[v + 1];
  if (beg >= end) return;
  int g = lane >> 4;
  int l = lane & 15;
  const float4* __restrict__ y4 = (const float4*)y;
  const float4* __restrict__ b14 = (const float4*)b1;
  const float4* __restrict__ w24 = (const float4*)w2;
  float4 d0 = y4[(size_t)v * 32 + l];
  float4 d1 = y4[(size_t)v * 32 + 16 + l];
  float4 bb0 = b14[l], bb1 = b14[16 + l];
  d0.x += bb0.x; d0.y += bb0.y; d0.z += bb0.z; d0.w += bb0.w;
  d1.x += bb1.x; d1.y += bb1.y; d1.z += bb1.z; d1.w += bb1.w;
  float4 w0 = w24[l], w1 = w24[16 + l];
  float ob2 = b2[0];
  for (int i = beg; i < end; i += 16) {
    int ii[4];
    bool qq[4];
    int ss[4];
#pragma unroll
    for (int u = 0; u < 4; ++u) {
      ii[u] = i + 4 * u + g;
      qq[u] = ii[u] < end;
      ss[u] = csr_src[qq[u] ? ii[u] : beg];
    }
    float4 A0[4], A1[4];
#pragma unroll
    for (int u = 0; u < 4; ++u) {
      A0[u] = y4[(size_t)ss[u] * 32 + l];
      A1[u] = y4[(size_t)ss[u] * 32 + 16 + l];
    }
#pragma unroll
    for (int u = 0; u < 4; ++u) {
      float p = fmaxf(A0[u].x + d0.x, 0.f) * w0.x + fmaxf(A0[u].y + d0.y, 0.f) * w0.y +
                fmaxf(A0[u].z + d0.z, 0.f) * w0.z + fmaxf(A0[u].w + d0.w, 0.f) * w0.w +
                fmaxf(A1[u].x + d1.x, 0.f) * w1.x + fmaxf(A1[u].y + d1.y, 0.f) * w1.y +
                fmaxf(A1[u].z + d1.z, 0.f) * w1.z + fmaxf(A1[u].w + d1.w, 0.f) * w1.w;
      p += __shfl_down(p, 8, 16);
      p += __shfl_down(p, 4, 16);
      p += __shfl_down(p, 2, 16);
      p += __shfl_down(p, 1, 16);
      if (l == 0 && qq[u]) out[csr_eid[ii[u]]] = p + ob2;
    }
  }
}

extern "C" void kernel_launch(void* const* d_in, const int* in_sizes, int n_in,
                              void* d_out, int out_size, void* d_ws, size_t ws_size,
                              hipStream_t stream) {
  const float* node_feats = (const float*)d_in[1];
  const int*   src        = (const int*)d_in[2];
  const int*   dst        = (const int*)d_in[3];
  const float* W_nemb     = (const float*)d_in[6];
  const float* b_nemb     = (const float*)d_in[7];
  const float* gnn_W      = (const float*)d_in[8];
  const float* gnn_b      = (const float*)d_in[9];
  const float* out_W1     = (const float*)d_in[10];
  const float* out_b1     = (const float*)d_in[11];
  const float* out_W2     = (const float*)d_in[12];
  const float* out_b2     = (const float*)d_in[13];
  float* out = (float*)d_out;

  size_t off = 0;
  char* base = (char*)d_ws;
  auto alloc = [&](size_t nbytes) -> char* {
    off = (off + 255) & ~(size_t)255;
    char* p = base + off;
    off += nbytes;
    return p;
  };
  int*    cnt_out  = (int*)alloc(N_NODES * 4);
  int*    cnt_in   = (int*)alloc(N_NODES * 4);
  float*  norm_out = (float*)alloc(N_NODES * 4);
  float*  norm_in  = (float*)alloc(N_NODES * 4);
  int*    row_ofs  = (int*)alloc((N_NODES + 1) * 4);
  int*    cursor   = (int*)alloc(N_NODES * 4);
  int*    blk_sums = (int*)alloc(SCAN_BLK * 4);
  int*    blk_base = (int*)alloc(SCAN_BLK * 4);
  int*    csr_src  = (int*)alloc((size_t)N_EDGES * 4);
  int*    csr_eid  = (int*)alloc((size_t)N_EDGES * 4);
  float4* agg4     = (float4*)alloc((size_t)N_NODES * 16);
  float*  sno      = (float*)alloc(N_NODES * 4);
  float*  buf_a    = (float*)alloc((size_t)N_NODES * HID * 4);
  float*  buf_b    = (float*)alloc((size_t)N_NODES * HID * 4);
  (void)ws_size; (void)n_in; (void)in_sizes; (void)out_size;

  const int nb_scan = (N_NODES + SCAN_BLK - 1) / SCAN_BLK;

  hipMemsetAsync(cnt_out, 0, N_NODES * 4, stream);
  hipMemsetAsync(cnt_in, 0, N_NODES * 4, stream);
  deg_kernel<<<(N_EDGES + 255) / 256, 256, 0, stream>>>(src, dst, cnt_out, cnt_in);
  norm_kernel<<<nb_scan, 256, 0, stream>>>(cnt_out, cnt_in, norm_out, norm_in);

  scan_blocks_kernel<<<nb_scan, SCAN_BLK, 0, stream>>>(cnt_in, row_ofs, blk_sums, N_NODES);
  scan_sums_kernel<<<1, SCAN_BLK, 0, stream>>>(blk_sums, blk_base, nb_scan);
  add_base_kernel<<<nb_scan, 256, 0, stream>>>(row_ofs, blk_base, cursor, N_NODES, N_EDGES);
  csr_fill_kernel<<<(N_EDGES + 255) / 256, 256, 0, stream>>>(src, dst, cursor, csr_src, csr_eid);

  agg4_kernel<<<(N_NODES * 16 + 255) / 256, 256, 0, stream>>>(
      (const float4*)node_feats, norm_out, csr_src, row_ofs, agg4, sno);
  gemm_l1_kernel<<<(N_NODES + 63) / 64, 256, 0, stream>>>(
      agg4, sno, norm_in, norm_out, W_nemb, b_nemb, gnn_W, gnn_b, buf_a, N_NODES);

  aggregate_kernel<<<(N_NODES * 64 + 255) / 256, 256, 0, stream>>>(
      buf_a, row_ofs, csr_src, norm_in, buf_b);

  gemm_dual_kernel<<<(N_NODES + 63) / 64, 256, 0, stream>>>(
      buf_b, gnn_W + (size_t)HID * HID, gnn_b + HID, out_W1, buf_a, N_NODES);

  edge_out_kernel<<<(N_NODES * 64 + 255) / 256, 256, 0, stream>>>(
      csr_src, csr_eid, row_ofs, buf_a, out_b1, out_W2, out_b2, out);
}

// Round 7
// 389.992 us; speedup vs baseline: 1.1538x; 1.1538x over previous
//
#include <hip/hip_runtime.h>

#define N_NODES 50000
#define N_EDGES 800000
#define HID 128
#define AP 133   // padded row stride for As; bank = (5*row + col) % 32
#define NB 256   // node buckets
#define NPB 196  // nodes per bucket (256*196 >= 50000)

// ================= bucketed CSR build (no per-edge global atomics) =================

// Phase 1: per-bucket edge counts (dst buckets and src buckets)
__global__ __launch_bounds__(256) void p1_hist_kernel(
    const int* __restrict__ src, const int* __restrict__ dst,
    int* __restrict__ bcnt_d, int* __restrict__ bcnt_s) {
  __shared__ int hd[NB], hs[NB];
  int t = threadIdx.x;
  hd[t] = 0; hs[t] = 0;
  __syncthreads();
  for (int e = blockIdx.x * 256 + t; e < N_EDGES; e += gridDim.x * 256) {
    atomicAdd(&hd[dst[e] / NPB], 1);
    atomicAdd(&hs[src[e] / NPB], 1);
  }
  __syncthreads();
  if (hd[t]) atomicAdd(&bcnt_d[t], hd[t]);
  if (hs[t]) atomicAdd(&bcnt_s[t], hs[t]);
}

// Phase 2: exclusive scan of both bucket-count arrays; init cursors
__global__ void p2_scan_kernel(const int* __restrict__ bcnt_d, const int* __restrict__ bcnt_s,
                               int* __restrict__ bofs_d, int* __restrict__ bofs_s,
                               int* __restrict__ cur_d, int* __restrict__ cur_s) {
  __shared__ int s[NB];
  int t = threadIdx.x;
  int v = bcnt_d[t];
  s[t] = v;
  __syncthreads();
  for (int o = 1; o < NB; o <<= 1) {
    int x = (t >= o) ? s[t - o] : 0;
    __syncthreads();
    s[t] += x;
    __syncthreads();
  }
  int ofs = s[t] - v;
  bofs_d[t] = ofs; cur_d[t] = ofs;
  if (t == NB - 1) bofs_d[NB] = s[t];
  __syncthreads();
  v = bcnt_s[t];
  s[t] = v;
  __syncthreads();
  for (int o = 1; o < NB; o <<= 1) {
    int x = (t >= o) ? s[t - o] : 0;
    __syncthreads();
    s[t] += x;
    __syncthreads();
  }
  ofs = s[t] - v;
  bofs_s[t] = ofs; cur_s[t] = ofs;
  if (t == NB - 1) bofs_s[NB] = s[t];
}

// Phase 3a: scatter edges into dst-bucket-grouped storage.
// 2048 edges per block; block reserves per-bucket ranges with ONE global atomic per bucket.
__global__ __launch_bounds__(256) void p3_scatter_dst_kernel(
    const int* __restrict__ src, const int* __restrict__ dst,
    int* __restrict__ cur_d, int2* __restrict__ sdst) {
  __shared__ int bcnt[NB], bbase[NB];
  int t = threadIdx.x;
  int base = blockIdx.x * 2048;
  bcnt[t] = 0;
  __syncthreads();
  int myb[8], myr[8], mys[8], myp[8];
#pragma unroll
  for (int u = 0; u < 8; ++u) {
    int e = base + u * 256 + t;
    myb[u] = -1;
    if (e < N_EDGES) {
      int d = dst[e];
      int b = d / NPB;
      myb[u] = b;
      myr[u] = atomicAdd(&bcnt[b], 1);
      mys[u] = src[e];
      myp[u] = ((d - b * NPB) << 20) | e;
    }
  }
  __syncthreads();
  int c = bcnt[t];
  if (c) bbase[t] = atomicAdd(&cur_d[t], c);
  __syncthreads();
#pragma unroll
  for (int u = 0; u < 8; ++u) {
    if (myb[u] >= 0) sdst[bbase[myb[u]] + myr[u]] = make_int2(mys[u], myp[u]);
  }
}

// Phase 3b: scatter bare src values into src-bucket-grouped storage (for out-degrees)
__global__ __launch_bounds__(256) void p3_scatter_src_kernel(
    const int* __restrict__ src, int* __restrict__ cur_s, int* __restrict__ ssrc) {
  __shared__ int bcnt[NB], bbase[NB];
  int t = threadIdx.x;
  int base = blockIdx.x * 2048;
  bcnt[t] = 0;
  __syncthreads();
  int myb[8], myr[8], mys[8];
#pragma unroll
  for (int u = 0; u < 8; ++u) {
    int e = base + u * 256 + t;
    myb[u] = -1;
    if (e < N_EDGES) {
      int s = src[e];
      int b = s / NPB;
      myb[u] = b;
      myr[u] = atomicAdd(&bcnt[b], 1);
      mys[u] = s;
    }
  }
  __syncthreads();
  int c = bcnt[t];
  if (c) bbase[t] = atomicAdd(&cur_s[t], c);
  __syncthreads();
#pragma unroll
  for (int u = 0; u < 8; ++u) {
    if (myb[u] >= 0) ssrc[bbase[myb[u]] + myr[u]] = mys[u];
  }
}

// Phase 4: one block per dst-bucket -> row_ofs, norm_in, dst-grouped csr_src/csr_eid
__global__ __launch_bounds__(256) void p4_csr_kernel(
    const int2* __restrict__ sdst, const int* __restrict__ bofs_d,
    int* __restrict__ row_ofs, float* __restrict__ norm_in,
    int* __restrict__ csr_src, int* __restrict__ csr_eid) {
  __shared__ int hc[NB], sc[NB], cur[NB];
  int b = blockIdx.x, t = threadIdx.x;
  int base = bofs_d[b], cnt = bofs_d[b + 1] - base;
  hc[t] = 0;
  __syncthreads();
  for (int i = t; i < cnt; i += 256) atomicAdd(&hc[sdst[base + i].y >> 20], 1);
  __syncthreads();
  int v = hc[t];
  sc[t] = v;
  __syncthreads();
  for (int o = 1; o < NB; o <<= 1) {
    int x = (t >= o) ? sc[t - o] : 0;
    __syncthreads();
    sc[t] += x;
    __syncthreads();
  }
  int ofs = sc[t] - v;
  int node = b * NPB + t;
  if (t < NPB && node < N_NODES) {
    row_ofs[node] = base + ofs;
    norm_in[node] = rsqrtf((float)(v < 1 ? 1 : v));
  }
  cur[t] = base + ofs;
  if (b == 0 && t == 0) row_ofs[N_NODES] = N_EDGES;
  __syncthreads();
  for (int i = t; i < cnt; i += 256) {
    int2 e = sdst[base + i];
    int pos = atomicAdd(&cur[e.y >> 20], 1);
    csr_src[pos] = e.x;
    csr_eid[pos] = e.y & 0xFFFFF;
  }
}

// Phase 5: one block per src-bucket -> norm_out
__global__ __launch_bounds__(256) void p5_degout_kernel(
    const int* __restrict__ ssrc, const int* __restrict__ bofs_s,
    float* __restrict__ norm_out) {
  __shared__ int hc[NB];
  int b = blockIdx.x, t = threadIdx.x;
  int base = bofs_s[b], cnt = bofs_s[b + 1] - base;
  int lo = b * NPB;
  hc[t] = 0;
  __syncthreads();
  for (int i = t; i < cnt; i += 256) atomicAdd(&hc[ssrc[base + i] - lo], 1);
  __syncthreads();
  int node = lo + t;
  if (t < NPB && node < N_NODES) {
    int v = hc[t];
    norm_out[node] = rsqrtf((float)(v < 1 ? 1 : v));
  }
}

// ================= model kernels (unchanged from R5) =================

__global__ __launch_bounds__(256) void agg4_kernel(
    const float4* __restrict__ nf4, const float* __restrict__ no_,
    const int* __restrict__ csr_src, const int* __restrict__ row_ofs,
    float4* __restrict__ agg4, float* __restrict__ sno) {
  int wid = (blockIdx.x * blockDim.x + threadIdx.x) >> 6;
  int lane = threadIdx.x & 63;
  int g = lane >> 4, l = lane & 15;
  int v = wid * 4 + g;
  if (v >= N_NODES) return;
  int beg = row_ofs[v], end = row_ofs[v + 1];
  float ax = 0.f, ay = 0.f, az = 0.f, aw = 0.f, sn = 0.f;
  for (int i = beg + l; i < end; i += 16) {
    int s = csr_src[i];
    float w = no_[s];
    float4 n = nf4[s];
    ax += n.x * w; ay += n.y * w; az += n.z * w; aw += n.w * w;
    sn += w;
  }
#pragma unroll
  for (int o = 1; o < 16; o <<= 1) {
    ax += __shfl_xor(ax, o, 16);
    ay += __shfl_xor(ay, o, 16);
    az += __shfl_xor(az, o, 16);
    aw += __shfl_xor(aw, o, 16);
    sn += __shfl_xor(sn, o, 16);
  }
  if (l == 0) {
    agg4[v] = make_float4(ax, ay, az, aw);
    sno[v] = sn;
  }
}

__global__ __launch_bounds__(256) void gemm_l1_kernel(
    const float4* __restrict__ agg4, const float* __restrict__ sno,
    const float* __restrict__ ni_, const float* __restrict__ no_,
    const float* __restrict__ Wn, const float* __restrict__ bn,
    const float* __restrict__ W0, const float* __restrict__ b0,
    float* __restrict__ out, int nrows) {
  __shared__ float At[HID * 64];      // 32 KB, k-major
  __shared__ float Wbuf[32 * HID];    // 16 KB
  int t = threadIdx.x;
  int v0 = blockIdx.x * 64;
  {
    int r = t & 63, kg = t >> 6;
    int v = v0 + r;
    float4 a = make_float4(0.f, 0.f, 0.f, 0.f);
    float sn = 0.f, nin = 0.f;
    if (v < nrows) { a = agg4[v]; sn = sno[v]; nin = ni_[v]; }
    for (int kk = 0; kk < 32; ++kk) {
      int k = kg * 32 + kk;  // wave-uniform
      float val = (a.x * Wn[k] + a.y * Wn[HID + k] + a.z * Wn[2 * HID + k] +
                   a.w * Wn[3 * HID + k] + bn[k] * sn) * nin;
      At[k * 64 + r] = val;
    }
  }
  int c0 = (t >> 4) * 8, r0 = (t & 15) * 4;
  float acc[4][8];
#pragma unroll
  for (int i = 0; i < 4; ++i)
#pragma unroll
    for (int j = 0; j < 8; ++j) acc[i][j] = 0.f;

  for (int kc = 0; kc < HID; kc += 32) {
    __syncthreads();
    {
      const float4* wsrc = (const float4*)(W0 + kc * HID);
      float4* wdst = (float4*)Wbuf;
#pragma unroll
      for (int i = 0; i < 4; ++i) wdst[i * 256 + t] = wsrc[i * 256 + t];
    }
    __syncthreads();
#pragma unroll 4
    for (int kk = 0; kk < 32; ++kk) {
      float4 av = *(const float4*)&At[(kc + kk) * 64 + r0];
      float4 w0v = *(const float4*)&Wbuf[kk * HID + c0];
      float4 w1v = *(const float4*)&Wbuf[kk * HID + c0 + 4];
      float ar[4] = {av.x, av.y, av.z, av.w};
      float wv[8] = {w0v.x, w0v.y, w0v.z, w0v.w, w1v.x, w1v.y, w1v.z, w1v.w};
#pragma unroll
      for (int i = 0; i < 4; ++i)
#pragma unroll
        for (int j = 0; j < 8; ++j) acc[i][j] += ar[i] * wv[j];
    }
  }
  float bb[8];
  {
    float4 b0v = *(const float4*)&b0[c0];
    float4 b1v = *(const float4*)&b0[c0 + 4];
    bb[0] = b0v.x; bb[1] = b0v.y; bb[2] = b0v.z; bb[3] = b0v.w;
    bb[4] = b1v.x; bb[5] = b1v.y; bb[6] = b1v.z; bb[7] = b1v.w;
  }
#pragma unroll
  for (int i = 0; i < 4; ++i) {
    int v = v0 + r0 + i;
    if (v < nrows) {
      float nov = no_[v];
      float4 o0, o1;
      o0.x = fmaxf(acc[i][0] + bb[0], 0.f) * nov;
      o0.y = fmaxf(acc[i][1] + bb[1], 0.f) * nov;
      o0.z = fmaxf(acc[i][2] + bb[2], 0.f) * nov;
      o0.w = fmaxf(acc[i][3] + bb[3], 0.f) * nov;
      o1.x = fmaxf(acc[i][4] + bb[4], 0.f) * nov;
      o1.y = fmaxf(acc[i][5] + bb[5], 0.f) * nov;
      o1.z = fmaxf(acc[i][6] + bb[6], 0.f) * nov;
      o1.w = fmaxf(acc[i][7] + bb[7], 0.f) * nov;
      *(float4*)&out[(size_t)v * HID + c0] = o0;
      *(float4*)&out[(size_t)v * HID + c0 + 4] = o1;
    }
  }
}

__global__ __launch_bounds__(256) void aggregate_kernel(
    const float* __restrict__ h, const int* __restrict__ row_ofs,
    const int* __restrict__ csr_src, const float* __restrict__ ni_,
    float* __restrict__ agg) {
  int v = (blockIdx.x * blockDim.x + threadIdx.x) >> 6;
  int lane = threadIdx.x & 63;
  if (v >= N_NODES) return;
  int beg = row_ofs[v], end = row_ofs[v + 1];
  int g = lane >> 4, l = lane & 15;
  const float4* __restrict__ h4 = (const float4*)h;
  float a0x = 0.f, a0y = 0.f, a0z = 0.f, a0w = 0.f;
  float a1x = 0.f, a1y = 0.f, a1z = 0.f, a1w = 0.f;
  for (int i = beg; i < end; i += 16) {
    int ii[4];
    float mm[4];
    int ss[4];
#pragma unroll
    for (int u = 0; u < 4; ++u) {
      ii[u] = i + 4 * u + g;
      bool q = ii[u] < end;
      mm[u] = q ? 1.f : 0.f;
      ss[u] = csr_src[q ? ii[u] : beg];
    }
    float4 X0[4], X1[4];
#pragma unroll
    for (int u = 0; u < 4; ++u) {
      X0[u] = h4[(size_t)ss[u] * 32 + l];
      X1[u] = h4[(size_t)ss[u] * 32 + 16 + l];
    }
#pragma unroll
    for (int u = 0; u < 4; ++u) {
      a0x += X0[u].x * mm[u]; a0y += X0[u].y * mm[u];
      a0z += X0[u].z * mm[u]; a0w += X0[u].w * mm[u];
      a1x += X1[u].x * mm[u]; a1y += X1[u].y * mm[u];
      a1z += X1[u].z * mm[u]; a1w += X1[u].w * mm[u];
    }
  }
  a0x += __shfl_xor(a0x, 16, 64); a0x += __shfl_xor(a0x, 32, 64);
  a0y += __shfl_xor(a0y, 16, 64); a0y += __shfl_xor(a0y, 32, 64);
  a0z += __shfl_xor(a0z, 16, 64); a0z += __shfl_xor(a0z, 32, 64);
  a0w += __shfl_xor(a0w, 16, 64); a0w += __shfl_xor(a0w, 32, 64);
  a1x += __shfl_xor(a1x, 16, 64); a1x += __shfl_xor(a1x, 32, 64);
  a1y += __shfl_xor(a1y, 16, 64); a1y += __shfl_xor(a1y, 32, 64);
  a1z += __shfl_xor(a1z, 16, 64); a1z += __shfl_xor(a1z, 32, 64);
  a1w += __shfl_xor(a1w, 16, 64); a1w += __shfl_xor(a1w, 32, 64);
  if (g == 0) {
    float n = ni_[v];
    float4* a4 = (float4*)agg;
    a4[(size_t)v * 32 + l] = make_float4(a0x * n, a0y * n, a0z * n, a0w * n);
    a4[(size_t)v * 32 + 16 + l] = make_float4(a1x * n, a1y * n, a1z * n, a1w * n);
  }
}

__global__ __launch_bounds__(256) void gemm_dual_kernel(
    const float* __restrict__ in, const float* __restrict__ W0,
    const float* __restrict__ b0, const float* __restrict__ W1,
    float* __restrict__ out, int nrows) {
  __shared__ float As[64 * AP];
  __shared__ float Wbuf[32 * HID];
  int t = threadIdx.x;
  int v0 = blockIdx.x * 64;
  {
    const float4* in4 = (const float4*)in;
#pragma unroll
    for (int i = 0; i < 8; ++i) {
      int idx = i * 256 + t;
      int r = idx >> 5, q = idx & 31;
      int v = v0 + r;
      float4 val = make_float4(0.f, 0.f, 0.f, 0.f);
      if (v < nrows) val = in4[(size_t)v * 32 + q];
      float* p = &As[r * AP + q * 4];
      p[0] = val.x; p[1] = val.y; p[2] = val.z; p[3] = val.w;
    }
  }
  int c0 = (t >> 4) * 8, m = t & 15;
  float acc[4][8];
#pragma unroll
  for (int i = 0; i < 4; ++i)
#pragma unroll
    for (int j = 0; j < 8; ++j) acc[i][j] = 0.f;

  for (int kc = 0; kc < HID; kc += 32) {
    __syncthreads();
    {
      const float4* wsrc = (const float4*)(W0 + kc * HID);
      float4* wdst = (float4*)Wbuf;
#pragma unroll
      for (int i = 0; i < 4; ++i) wdst[i * 256 + t] = wsrc[i * 256 + t];
    }
    __syncthreads();
#pragma unroll 4
    for (int kk = 0; kk < 32; ++kk) {
      int k = kc + kk;
      float ar[4];
#pragma unroll
      for (int i = 0; i < 4; ++i) ar[i] = As[(m + 16 * i) * AP + k];
      float4 w0v = *(const float4*)&Wbuf[kk * HID + c0];
      float4 w1v = *(const float4*)&Wbuf[kk * HID + c0 + 4];
      float wv[8] = {w0v.x, w0v.y, w0v.z, w0v.w, w1v.x, w1v.y, w1v.z, w1v.w};
#pragma unroll
      for (int i = 0; i < 4; ++i)
#pragma unroll
        for (int j = 0; j < 8; ++j) acc[i][j] += ar[i] * wv[j];
    }
  }
  __syncthreads();
  {
    float bb[8];
    float4 b0v = *(const float4*)&b0[c0];
    float4 b1v = *(const float4*)&b0[c0 + 4];
    bb[0] = b0v.x; bb[1] = b0v.y; bb[2] = b0v.z; bb[3] = b0v.w;
    bb[4] = b1v.x; bb[5] = b1v.y; bb[6] = b1v.z; bb[7] = b1v.w;
#pragma unroll
    for (int i = 0; i < 4; ++i)
#pragma unroll
      for (int j = 0; j < 8; ++j) {
        As[(m + 16 * i) * AP + c0 + j] = fmaxf(acc[i][j] + bb[j], 0.f);
        acc[i][j] = 0.f;
      }
  }
  for (int kc = 0; kc < HID; kc += 32) {
    __syncthreads();
    {
      const float4* wsrc = (const float4*)(W1 + kc * HID);
      float4* wdst = (float4*)Wbuf;
#pragma unroll
      for (int i = 0; i < 4; ++i) wdst[i * 256 + t] = wsrc[i * 256 + t];
    }
    __syncthreads();
#pragma unroll 4
    for (int kk = 0; kk < 32; ++kk) {
      int k = kc + kk;
      float ar[4];
#pragma unroll
      for (int i = 0; i < 4; ++i) ar[i] = As[(m + 16 * i) * AP + k];
      float4 w0v = *(const float4*)&Wbuf[kk * HID + c0];
      float4 w1v = *(const float4*)&Wbuf[kk * HID + c0 + 4];
      float wv[8] = {w0v.x, w0v.y, w0v.z, w0v.w, w1v.x, w1v.y, w1v.z, w1v.w};
#pragma unroll
      for (int i = 0; i < 4; ++i)
#pragma unroll
        for (int j = 0; j < 8; ++j) acc[i][j] += ar[i] * wv[j];
    }
  }
#pragma unroll
  for (int i = 0; i < 4; ++i) {
    int v = v0 + m + 16 * i;
    if (v < nrows) {
      float4 o0 = make_float4(acc[i][0], acc[i][1], acc[i][2], acc[i][3]);
      float4 o1 = make_float4(acc[i][4], acc[i][5], acc[i][6], acc[i][7]);
      *(float4*)&out[(size_t)v * HID + c0] = o0;
      *(float4*)&out[(size_t)v * HID + c0 + 4] = o1;
    }
  }
}

__global__ __launch_bounds__(256) void edge_out_kernel(
    const int* __restrict__ csr_src, const int* __restrict__ csr_eid,
    const int* __restrict__ row_ofs, const float* __restrict__ y,
    const float* __restrict__ b1, const float* __restrict__ w2,
    const float* __restrict__ b2, float* __restrict__ out) {
  int v = (blockIdx.x * blockDim.x + threadIdx.x) >> 6;
  int lane = threadIdx.x & 63;
  if (v >= N_NODES) return;
  int beg = row_ofs[v], end = row_ofs[v + 1];
  if (beg >= end) return;
  int g = lane >> 4;
  int l = lane & 15;
  const float4* __restrict__ y4 = (const float4*)y;
  const float4* __restrict__ b14 = (const float4*)b1;
  const float4* __restrict__ w24 = (const float4*)w2;
  float4 d0 = y4[(size_t)v * 32 + l];
  float4 d1 = y4[(size_t)v * 32 + 16 + l];
  float4 bb0 = b14[l], bb1 = b14[16 + l];
  d0.x += bb0.x; d0.y += bb0.y; d0.z += bb0.z; d0.w += bb0.w;
  d1.x += bb1.x; d1.y += bb1.y; d1.z += bb1.z; d1.w += bb1.w;
  float4 w0 = w24[l], w1 = w24[16 + l];
  float ob2 = b2[0];
  for (int i = beg; i < end; i += 16) {
    int ii[4];
    bool qq[4];
    int ss[4];
#pragma unroll
    for (int u = 0; u < 4; ++u) {
      ii[u] = i + 4 * u + g;
      qq[u] = ii[u] < end;
      ss[u] = csr_src[qq[u] ? ii[u] : beg];
    }
    float4 A0[4], A1[4];
#pragma unroll
    for (int u = 0; u < 4; ++u) {
      A0[u] = y4[(size_t)ss[u] * 32 + l];
      A1[u] = y4[(size_t)ss[u] * 32 + 16 + l];
    }
#pragma unroll
    for (int u = 0; u < 4; ++u) {
      float p = fmaxf(A0[u].x + d0.x, 0.f) * w0.x + fmaxf(A0[u].y + d0.y, 0.f) * w0.y +
                fmaxf(A0[u].z + d0.z, 0.f) * w0.z + fmaxf(A0[u].w + d0.w, 0.f) * w0.w +
                fmaxf(A1[u].x + d1.x, 0.f) * w1.x + fmaxf(A1[u].y + d1.y, 0.f) * w1.y +
                fmaxf(A1[u].z + d1.z, 0.f) * w1.z + fmaxf(A1[u].w + d1.w, 0.f) * w1.w;
      p += __shfl_down(p, 8, 16);
      p += __shfl_down(p, 4, 16);
      p += __shfl_down(p, 2, 16);
      p += __shfl_down(p, 1, 16);
      if (l == 0 && qq[u]) out[csr_eid[ii[u]]] = p + ob2;
    }
  }
}

extern "C" void kernel_launch(void* const* d_in, const int* in_sizes, int n_in,
                              void* d_out, int out_size, void* d_ws, size_t ws_size,
                              hipStream_t stream) {
  const float* node_feats = (const float*)d_in[1];
  const int*   src        = (const int*)d_in[2];
  const int*   dst        = (const int*)d_in[3];
  const float* W_nemb     = (const float*)d_in[6];
  const float* b_nemb     = (const float*)d_in[7];
  const float* gnn_W      = (const float*)d_in[8];
  const float* gnn_b      = (const float*)d_in[9];
  const float* out_W1     = (const float*)d_in[10];
  const float* out_b1     = (const float*)d_in[11];
  const float* out_W2     = (const float*)d_in[12];
  const float* out_b2     = (const float*)d_in[13];
  float* out = (float*)d_out;

  size_t off = 0;
  char* base = (char*)d_ws;
  auto alloc = [&](size_t nbytes) -> char* {
    off = (off + 255) & ~(size_t)255;
    char* p = base + off;
    off += nbytes;
    return p;
  };
  int*    bcnt2    = (int*)alloc(2 * NB * 4);       // [bcnt_d | bcnt_s]
  int*    bofs_d   = (int*)alloc((NB + 1) * 4);
  int*    bofs_s   = (int*)alloc((NB + 1) * 4);
  int*    cur_d    = (int*)alloc(NB * 4);
  int*    cur_s    = (int*)alloc(NB * 4);
  float*  norm_out = (float*)alloc(N_NODES * 4);
  float*  norm_in  = (float*)alloc(N_NODES * 4);
  int*    row_ofs  = (int*)alloc((N_NODES + 1) * 4);
  int*    csr_src  = (int*)alloc((size_t)N_EDGES * 4);
  int*    csr_eid  = (int*)alloc((size_t)N_EDGES * 4);
  float4* agg4     = (float4*)alloc((size_t)N_NODES * 16);
  float*  sno      = (float*)alloc(N_NODES * 4);
  float*  buf_a    = (float*)alloc((size_t)N_NODES * HID * 4);
  float*  buf_b    = (float*)alloc((size_t)N_NODES * HID * 4);
  // scatter staging aliases (consumed before buf_a/buf_b are first written)
  int2*   sdst     = (int2*)buf_b;   // 6.4 MB, consumed by p4 (before aggregate writes buf_b)
  int*    ssrc     = (int*)buf_a;    // 3.2 MB, consumed by p5 (before gemm_l1 writes buf_a)
  int*    bcnt_d   = bcnt2;
  int*    bcnt_s   = bcnt2 + NB;
  (void)ws_size; (void)n_in; (void)in_sizes; (void)out_size;

  hipMemsetAsync(bcnt2, 0, 2 * NB * 4, stream);
  p1_hist_kernel<<<128, 256, 0, stream>>>(src, dst, bcnt_d, bcnt_s);
  p2_scan_kernel<<<1, 256, 0, stream>>>(bcnt_d, bcnt_s, bofs_d, bofs_s, cur_d, cur_s);
  p3_scatter_dst_kernel<<<(N_EDGES + 2047) / 2048, 256, 0, stream>>>(src, dst, cur_d, sdst);
  p3_scatter_src_kernel<<<(N_EDGES + 2047) / 2048, 256, 0, stream>>>(src, cur_s, ssrc);
  p4_csr_kernel<<<NB, 256, 0, stream>>>(sdst, bofs_d, row_ofs, norm_in, csr_src, csr_eid);
  p5_degout_kernel<<<NB, 256, 0, stream>>>(ssrc, bofs_s, norm_out);

  agg4_kernel<<<(N_NODES * 16 + 255) / 256, 256, 0, stream>>>(
      (const float4*)node_feats, norm_out, csr_src, row_ofs, agg4, sno);
  gemm_l1_kernel<<<(N_NODES + 63) / 64, 256, 0, stream>>>(
      agg4, sno, norm_in, norm_out, W_nemb, b_nemb, gnn_W, gnn_b, buf_a, N_NODES);

  aggregate_kernel<<<(N_NODES * 64 + 255) / 256, 256, 0, stream>>>(
      buf_a, row_ofs, csr_src, norm_in, buf_b);

  gemm_dual_kernel<<<(N_NODES + 63) / 64, 256, 0, stream>>>(
      buf_b, gnn_W + (size_t)HID * HID, gnn_b + HID, out_W1, buf_a, N_NODES);

  edge_out_kernel<<<(N_NODES * 64 + 255) / 256, 256, 0, stream>>>(
      csr_src, csr_eid, row_ofs, buf_a, out_b1, out_W2, out_b2, out);
}

// Round 8
// 345.700 us; speedup vs baseline: 1.3016x; 1.1281x over previous
//
#include <hip/hip_runtime.h>

#define N_NODES 50000
#define N_EDGES 800000
#define HID 128
#define AP2 132  // padded row stride (mult of 4 for b128; bank stride 4)
#define NB 256   // node buckets
#define NPB 196  // nodes per bucket

__device__ __forceinline__ unsigned pack2bf(float a, float b) {
  unsigned ua = __float_as_uint(a);
  ua += 0x7FFFu + ((ua >> 16) & 1u);
  unsigned ub = __float_as_uint(b);
  ub += 0x7FFFu + ((ub >> 16) & 1u);
  return (ua >> 16) | (ub & 0xFFFF0000u);
}
#define BFLO(u) __uint_as_float((u) << 16)
#define BFHI(u) __uint_as_float((u) & 0xFFFF0000u)

// ================= bucketed CSR build (unchanged from R6) =================

__global__ __launch_bounds__(256) void p1_hist_kernel(
    const int* __restrict__ src, const int* __restrict__ dst,
    int* __restrict__ bcnt_d, int* __restrict__ bcnt_s) {
  __shared__ int hd[NB], hs[NB];
  int t = threadIdx.x;
  hd[t] = 0; hs[t] = 0;
  __syncthreads();
  for (int e = blockIdx.x * 256 + t; e < N_EDGES; e += gridDim.x * 256) {
    atomicAdd(&hd[dst[e] / NPB], 1);
    atomicAdd(&hs[src[e] / NPB], 1);
  }
  __syncthreads();
  if (hd[t]) atomicAdd(&bcnt_d[t], hd[t]);
  if (hs[t]) atomicAdd(&bcnt_s[t], hs[t]);
}

__global__ void p2_scan_kernel(const int* __restrict__ bcnt_d, const int* __restrict__ bcnt_s,
                               int* __restrict__ bofs_d, int* __restrict__ bofs_s,
                               int* __restrict__ cur_d, int* __restrict__ cur_s) {
  __shared__ int s[NB];
  int t = threadIdx.x;
  int v = bcnt_d[t];
  s[t] = v;
  __syncthreads();
  for (int o = 1; o < NB; o <<= 1) {
    int x = (t >= o) ? s[t - o] : 0;
    __syncthreads();
    s[t] += x;
    __syncthreads();
  }
  int ofs = s[t] - v;
  bofs_d[t] = ofs; cur_d[t] = ofs;
  if (t == NB - 1) bofs_d[NB] = s[t];
  __syncthreads();
  v = bcnt_s[t];
  s[t] = v;
  __syncthreads();
  for (int o = 1; o < NB; o <<= 1) {
    int x = (t >= o) ? s[t - o] : 0;
    __syncthreads();
    s[t] += x;
    __syncthreads();
  }
  ofs = s[t] - v;
  bofs_s[t] = ofs; cur_s[t] = ofs;
  if (t == NB - 1) bofs_s[NB] = s[t];
}

__global__ __launch_bounds__(256) void p3_scatter_dst_kernel(
    const int* __restrict__ src, const int* __restrict__ dst,
    int* __restrict__ cur_d, int2* __restrict__ sdst) {
  __shared__ int bcnt[NB], bbase[NB];
  int t = threadIdx.x;
  int base = blockIdx.x * 2048;
  bcnt[t] = 0;
  __syncthreads();
  int myb[8], myr[8], mys[8], myp[8];
#pragma unroll
  for (int u = 0; u < 8; ++u) {
    int e = base + u * 256 + t;
    myb[u] = -1;
    if (e < N_EDGES) {
      int d = dst[e];
      int b = d / NPB;
      myb[u] = b;
      myr[u] = atomicAdd(&bcnt[b], 1);
      mys[u] = src[e];
      myp[u] = ((d - b * NPB) << 20) | e;
    }
  }
  __syncthreads();
  int c = bcnt[t];
  if (c) bbase[t] = atomicAdd(&cur_d[t], c);
  __syncthreads();
#pragma unroll
  for (int u = 0; u < 8; ++u) {
    if (myb[u] >= 0) sdst[bbase[myb[u]] + myr[u]] = make_int2(mys[u], myp[u]);
  }
}

__global__ __launch_bounds__(256) void p3_scatter_src_kernel(
    const int* __restrict__ src, int* __restrict__ cur_s, int* __restrict__ ssrc) {
  __shared__ int bcnt[NB], bbase[NB];
  int t = threadIdx.x;
  int base = blockIdx.x * 2048;
  bcnt[t] = 0;
  __syncthreads();
  int myb[8], myr[8], mys[8];
#pragma unroll
  for (int u = 0; u < 8; ++u) {
    int e = base + u * 256 + t;
    myb[u] = -1;
    if (e < N_EDGES) {
      int s = src[e];
      int b = s / NPB;
      myb[u] = b;
      myr[u] = atomicAdd(&bcnt[b], 1);
      mys[u] = s;
    }
  }
  __syncthreads();
  int c = bcnt[t];
  if (c) bbase[t] = atomicAdd(&cur_s[t], c);
  __syncthreads();
#pragma unroll
  for (int u = 0; u < 8; ++u) {
    if (myb[u] >= 0) ssrc[bbase[myb[u]] + myr[u]] = mys[u];
  }
}

__global__ __launch_bounds__(256) void p4_csr_kernel(
    const int2* __restrict__ sdst, const int* __restrict__ bofs_d,
    int* __restrict__ row_ofs, float* __restrict__ norm_in,
    int* __restrict__ csr_src, int* __restrict__ csr_eid) {
  __shared__ int hc[NB], sc[NB], cur[NB];
  int b = blockIdx.x, t = threadIdx.x;
  int base = bofs_d[b], cnt = bofs_d[b + 1] - base;
  hc[t] = 0;
  __syncthreads();
  for (int i = t; i < cnt; i += 256) atomicAdd(&hc[sdst[base + i].y >> 20], 1);
  __syncthreads();
  int v = hc[t];
  sc[t] = v;
  __syncthreads();
  for (int o = 1; o < NB; o <<= 1) {
    int x = (t >= o) ? sc[t - o] : 0;
    __syncthreads();
    sc[t] += x;
    __syncthreads();
  }
  int ofs = sc[t] - v;
  int node = b * NPB + t;
  if (t < NPB && node < N_NODES) {
    row_ofs[node] = base + ofs;
    norm_in[node] = rsqrtf((float)(v < 1 ? 1 : v));
  }
  cur[t] = base + ofs;
  if (b == 0 && t == 0) row_ofs[N_NODES] = N_EDGES;
  __syncthreads();
  for (int i = t; i < cnt; i += 256) {
    int2 e = sdst[base + i];
    int pos = atomicAdd(&cur[e.y >> 20], 1);
    csr_src[pos] = e.x;
    csr_eid[pos] = e.y & 0xFFFFF;
  }
}

__global__ __launch_bounds__(256) void p5_degout_kernel(
    const int* __restrict__ ssrc, const int* __restrict__ bofs_s,
    float* __restrict__ norm_out) {
  __shared__ int hc[NB];
  int b = blockIdx.x, t = threadIdx.x;
  int base = bofs_s[b], cnt = bofs_s[b + 1] - base;
  int lo = b * NPB;
  hc[t] = 0;
  __syncthreads();
  for (int i = t; i < cnt; i += 256) atomicAdd(&hc[ssrc[base + i] - lo], 1);
  __syncthreads();
  int node = lo + t;
  if (t < NPB && node < N_NODES) {
    int v = hc[t];
    norm_out[node] = rsqrtf((float)(v < 1 ? 1 : v));
  }
}

// ================= model kernels =================

__global__ __launch_bounds__(256) void agg4_kernel(
    const float4* __restrict__ nf4, const float* __restrict__ no_,
    const int* __restrict__ csr_src, const int* __restrict__ row_ofs,
    float4* __restrict__ agg4, float* __restrict__ sno) {
  int wid = (blockIdx.x * blockDim.x + threadIdx.x) >> 6;
  int lane = threadIdx.x & 63;
  int g = lane >> 4, l = lane & 15;
  int v = wid * 4 + g;
  if (v >= N_NODES) return;
  int beg = row_ofs[v], end = row_ofs[v + 1];
  float ax = 0.f, ay = 0.f, az = 0.f, aw = 0.f, sn = 0.f;
  for (int i = beg + l; i < end; i += 16) {
    int s = csr_src[i];
    float w = no_[s];
    float4 n = nf4[s];
    ax += n.x * w; ay += n.y * w; az += n.z * w; aw += n.w * w;
    sn += w;
  }
#pragma unroll
  for (int o = 1; o < 16; o <<= 1) {
    ax += __shfl_xor(ax, o, 16);
    ay += __shfl_xor(ay, o, 16);
    az += __shfl_xor(az, o, 16);
    aw += __shfl_xor(aw, o, 16);
    sn += __shfl_xor(sn, o, 16);
  }
  if (l == 0) {
    agg4[v] = make_float4(ax, ay, az, aw);
    sno[v] = sn;
  }
}

// layer-1: fused 4->128 expand + GEMM; output h1*norm_out packed bf16
__global__ __launch_bounds__(256) void gemm_l1_kernel(
    const float4* __restrict__ agg4, const float* __restrict__ sno,
    const float* __restrict__ ni_, const float* __restrict__ no_,
    const float* __restrict__ Wn, const float* __restrict__ bn,
    const float* __restrict__ W0, const float* __restrict__ b0,
    uint4* __restrict__ h1b, int nrows) {
  __shared__ float At[HID * 64];      // 32 KB, k-major
  __shared__ float Wbuf[32 * HID];    // 16 KB
  int t = threadIdx.x;
  int v0 = blockIdx.x * 64;
  {
    int r = t & 63, kg = t >> 6;
    int v = v0 + r;
    float4 a = make_float4(0.f, 0.f, 0.f, 0.f);
    float sn = 0.f, nin = 0.f;
    if (v < nrows) { a = agg4[v]; sn = sno[v]; nin = ni_[v]; }
    for (int kk = 0; kk < 32; ++kk) {
      int k = kg * 32 + kk;  // wave-uniform
      float val = (a.x * Wn[k] + a.y * Wn[HID + k] + a.z * Wn[2 * HID + k] +
                   a.w * Wn[3 * HID + k] + bn[k] * sn) * nin;
      At[k * 64 + r] = val;
    }
  }
  int c0 = (t >> 4) * 8, r0 = (t & 15) * 4;
  float acc[4][8];
#pragma unroll
  for (int i = 0; i < 4; ++i)
#pragma unroll
    for (int j = 0; j < 8; ++j) acc[i][j] = 0.f;

  for (int kc = 0; kc < HID; kc += 32) {
    __syncthreads();
    {
      const float4* wsrc = (const float4*)(W0 + kc * HID);
      float4* wdst = (float4*)Wbuf;
#pragma unroll
      for (int i = 0; i < 4; ++i) wdst[i * 256 + t] = wsrc[i * 256 + t];
    }
    __syncthreads();
#pragma unroll 4
    for (int kk = 0; kk < 32; ++kk) {
      float4 av = *(const float4*)&At[(kc + kk) * 64 + r0];
      float4 w0v = *(const float4*)&Wbuf[kk * HID + c0];
      float4 w1v = *(const float4*)&Wbuf[kk * HID + c0 + 4];
      float ar[4] = {av.x, av.y, av.z, av.w};
      float wv[8] = {w0v.x, w0v.y, w0v.z, w0v.w, w1v.x, w1v.y, w1v.z, w1v.w};
#pragma unroll
      for (int i = 0; i < 4; ++i)
#pragma unroll
        for (int j = 0; j < 8; ++j) acc[i][j] += ar[i] * wv[j];
    }
  }
  float bb[8];
  {
    float4 b0v = *(const float4*)&b0[c0];
    float4 b1v = *(const float4*)&b0[c0 + 4];
    bb[0] = b0v.x; bb[1] = b0v.y; bb[2] = b0v.z; bb[3] = b0v.w;
    bb[4] = b1v.x; bb[5] = b1v.y; bb[6] = b1v.z; bb[7] = b1v.w;
  }
#pragma unroll
  for (int i = 0; i < 4; ++i) {
    int v = v0 + r0 + i;
    if (v < nrows) {
      float nov = no_[v];
      float o[8];
#pragma unroll
      for (int j = 0; j < 8; ++j) o[j] = fmaxf(acc[i][j] + bb[j], 0.f) * nov;
      uint4 pk;
      pk.x = pack2bf(o[0], o[1]); pk.y = pack2bf(o[2], o[3]);
      pk.z = pack2bf(o[4], o[5]); pk.w = pack2bf(o[6], o[7]);
      h1b[(size_t)v * 16 + (c0 >> 3)] = pk;
    }
  }
}

// layer-2 aggregate: bf16 row gathers (256B/row), f32 accumulate
__global__ __launch_bounds__(256) void aggregate_kernel(
    const uint4* __restrict__ hb, const int* __restrict__ row_ofs,
    const int* __restrict__ csr_src, const float* __restrict__ ni_,
    float* __restrict__ agg) {
  int v = (blockIdx.x * blockDim.x + threadIdx.x) >> 6;
  int lane = threadIdx.x & 63;
  if (v >= N_NODES) return;
  int beg = row_ofs[v], end = row_ofs[v + 1];
  int g = lane >> 4, l = lane & 15;
  float acc[8];
#pragma unroll
  for (int j = 0; j < 8; ++j) acc[j] = 0.f;
  for (int i = beg; i < end; i += 16) {
    int ii[4]; float mm[4]; int ss[4];
#pragma unroll
    for (int u = 0; u < 4; ++u) {
      ii[u] = i + 4 * u + g;
      bool q = ii[u] < end;
      mm[u] = q ? 1.f : 0.f;
      ss[u] = csr_src[q ? ii[u] : beg];
    }
    uint4 X[4];
#pragma unroll
    for (int u = 0; u < 4; ++u) X[u] = hb[(size_t)ss[u] * 16 + l];
#pragma unroll
    for (int u = 0; u < 4; ++u) {
      acc[0] += BFLO(X[u].x) * mm[u]; acc[1] += BFHI(X[u].x) * mm[u];
      acc[2] += BFLO(X[u].y) * mm[u]; acc[3] += BFHI(X[u].y) * mm[u];
      acc[4] += BFLO(X[u].z) * mm[u]; acc[5] += BFHI(X[u].z) * mm[u];
      acc[6] += BFLO(X[u].w) * mm[u]; acc[7] += BFHI(X[u].w) * mm[u];
    }
  }
#pragma unroll
  for (int j = 0; j < 8; ++j) {
    acc[j] += __shfl_xor(acc[j], 16, 64);
    acc[j] += __shfl_xor(acc[j], 32, 64);
  }
  if (g == 0) {
    float n = ni_[v];
    float4 o0 = make_float4(acc[0] * n, acc[1] * n, acc[2] * n, acc[3] * n);
    float4 o1 = make_float4(acc[4] * n, acc[5] * n, acc[6] * n, acc[7] * n);
    *(float4*)&agg[(size_t)v * HID + l * 8] = o0;
    *(float4*)&agg[(size_t)v * HID + l * 8 + 4] = o1;
  }
}

// fused layer-2 GEMM + output GEMM; all-b128 LDS reads; y output packed bf16
__global__ __launch_bounds__(256) void gemm_dual_kernel(
    const float* __restrict__ in, const float* __restrict__ W0,
    const float* __restrict__ b0, const float* __restrict__ W1,
    uint4* __restrict__ yb, int nrows) {
  __shared__ float As[64 * AP2];      // 33 KB
  __shared__ float Wbuf[32 * HID];    // 16 KB
  int t = threadIdx.x;
  int v0 = blockIdx.x * 64;
  {
    const float4* in4 = (const float4*)in;
#pragma unroll
    for (int i = 0; i < 8; ++i) {
      int idx = i * 256 + t;
      int r = idx >> 5, q = idx & 31;
      int v = v0 + r;
      float4 val = make_float4(0.f, 0.f, 0.f, 0.f);
      if (v < nrows) val = in4[(size_t)v * 32 + q];
      *(float4*)&As[r * AP2 + q * 4] = val;
    }
  }
  int c0 = (t >> 4) * 8, m = t & 15;
  float acc[4][8];
#pragma unroll
  for (int i = 0; i < 4; ++i)
#pragma unroll
    for (int j = 0; j < 8; ++j) acc[i][j] = 0.f;

  // ---- GEMM 1: acc = A @ W0 ----
  for (int kc = 0; kc < HID; kc += 32) {
    __syncthreads();
    {
      const float4* wsrc = (const float4*)(W0 + kc * HID);
      float4* wdst = (float4*)Wbuf;
#pragma unroll
      for (int i = 0; i < 4; ++i) wdst[i * 256 + t] = wsrc[i * 256 + t];
    }
    __syncthreads();
#pragma unroll 2
    for (int k4 = 0; k4 < 8; ++k4) {
      float ak[4][4];
#pragma unroll
      for (int i = 0; i < 4; ++i) {
        float4 a4 = *(const float4*)&As[(m + 16 * i) * AP2 + kc + k4 * 4];
        ak[i][0] = a4.x; ak[i][1] = a4.y; ak[i][2] = a4.z; ak[i][3] = a4.w;
      }
#pragma unroll
      for (int kk = 0; kk < 4; ++kk) {
        float4 w0v = *(const float4*)&Wbuf[(k4 * 4 + kk) * HID + c0];
        float4 w1v = *(const float4*)&Wbuf[(k4 * 4 + kk) * HID + c0 + 4];
        float wv[8] = {w0v.x, w0v.y, w0v.z, w0v.w, w1v.x, w1v.y, w1v.z, w1v.w};
#pragma unroll
        for (int i = 0; i < 4; ++i)
#pragma unroll
          for (int j = 0; j < 8; ++j) acc[i][j] += ak[i][kk] * wv[j];
      }
    }
  }
  __syncthreads();
  {
    float bb[8];
    float4 b0v = *(const float4*)&b0[c0];
    float4 b1v = *(const float4*)&b0[c0 + 4];
    bb[0] = b0v.x; bb[1] = b0v.y; bb[2] = b0v.z; bb[3] = b0v.w;
    bb[4] = b1v.x; bb[5] = b1v.y; bb[6] = b1v.z; bb[7] = b1v.w;
#pragma unroll
    for (int i = 0; i < 4; ++i) {
      float4 o0, o1;
      o0.x = fmaxf(acc[i][0] + bb[0], 0.f); o0.y = fmaxf(acc[i][1] + bb[1], 0.f);
      o0.z = fmaxf(acc[i][2] + bb[2], 0.f); o0.w = fmaxf(acc[i][3] + bb[3], 0.f);
      o1.x = fmaxf(acc[i][4] + bb[4], 0.f); o1.y = fmaxf(acc[i][5] + bb[5], 0.f);
      o1.z = fmaxf(acc[i][6] + bb[6], 0.f); o1.w = fmaxf(acc[i][7] + bb[7], 0.f);
      *(float4*)&As[(m + 16 * i) * AP2 + c0] = o0;
      *(float4*)&As[(m + 16 * i) * AP2 + c0 + 4] = o1;
#pragma unroll
      for (int j = 0; j < 8; ++j) acc[i][j] = 0.f;
    }
  }
  // ---- GEMM 2: acc = T1 @ W1 ----
  for (int kc = 0; kc < HID; kc += 32) {
    __syncthreads();
    {
      const float4* wsrc = (const float4*)(W1 + kc * HID);
      float4* wdst = (float4*)Wbuf;
#pragma unroll
      for (int i = 0; i < 4; ++i) wdst[i * 256 + t] = wsrc[i * 256 + t];
    }
    __syncthreads();
#pragma unroll 2
    for (int k4 = 0; k4 < 8; ++k4) {
      float ak[4][4];
#pragma unroll
      for (int i = 0; i < 4; ++i) {
        float4 a4 = *(const float4*)&As[(m + 16 * i) * AP2 + kc + k4 * 4];
        ak[i][0] = a4.x; ak[i][1] = a4.y; ak[i][2] = a4.z; ak[i][3] = a4.w;
      }
#pragma unroll
      for (int kk = 0; kk < 4; ++kk) {
        float4 w0v = *(const float4*)&Wbuf[(k4 * 4 + kk) * HID + c0];
        float4 w1v = *(const float4*)&Wbuf[(k4 * 4 + kk) * HID + c0 + 4];
        float wv[8] = {w0v.x, w0v.y, w0v.z, w0v.w, w1v.x, w1v.y, w1v.z, w1v.w};
#pragma unroll
        for (int i = 0; i < 4; ++i)
#pragma unroll
          for (int j = 0; j < 8; ++j) acc[i][j] += ak[i][kk] * wv[j];
      }
    }
  }
#pragma unroll
  for (int i = 0; i < 4; ++i) {
    int v = v0 + m + 16 * i;
    if (v < nrows) {
      uint4 pk;
      pk.x = pack2bf(acc[i][0], acc[i][1]); pk.y = pack2bf(acc[i][2], acc[i][3]);
      pk.z = pack2bf(acc[i][4], acc[i][5]); pk.w = pack2bf(acc[i][6], acc[i][7]);
      yb[(size_t)v * 16 + (c0 >> 3)] = pk;
    }
  }
}

// edge output: bf16 y gathers (256B/row), f32 math
__global__ __launch_bounds__(256) void edge_out_kernel(
    const int* __restrict__ csr_src, const int* __restrict__ csr_eid,
    const int* __restrict__ row_ofs, const uint4* __restrict__ yb,
    const float* __restrict__ b1, const float* __restrict__ w2,
    const float* __restrict__ b2, float* __restrict__ out) {
  int v = (blockIdx.x * blockDim.x + threadIdx.x) >> 6;
  int lane = threadIdx.x & 63;
  if (v >= N_NODES) return;
  int beg = row_ofs[v], end = row_ofs[v + 1];
  if (beg >= end) return;
  int g = lane >> 4, l = lane & 15;
  uint4 D = yb[(size_t)v * 16 + l];
  float d[8] = {BFLO(D.x), BFHI(D.x), BFLO(D.y), BFHI(D.y),
                BFLO(D.z), BFHI(D.z), BFLO(D.w), BFHI(D.w)};
  {
    float4 q0 = ((const float4*)b1)[l * 2], q1 = ((const float4*)b1)[l * 2 + 1];
    d[0] += q0.x; d[1] += q0.y; d[2] += q0.z; d[3] += q0.w;
    d[4] += q1.x; d[5] += q1.y; d[6] += q1.z; d[7] += q1.w;
  }
  float w[8];
  {
    float4 q0 = ((const float4*)w2)[l * 2], q1 = ((const float4*)w2)[l * 2 + 1];
    w[0] = q0.x; w[1] = q0.y; w[2] = q0.z; w[3] = q0.w;
    w[4] = q1.x; w[5] = q1.y; w[6] = q1.z; w[7] = q1.w;
  }
  float ob2 = b2[0];
  for (int i = beg; i < end; i += 16) {
    int ii[4]; bool qq[4]; int ss[4];
#pragma unroll
    for (int u = 0; u < 4; ++u) {
      ii[u] = i + 4 * u + g;
      qq[u] = ii[u] < end;
      ss[u] = csr_src[qq[u] ? ii[u] : beg];
    }
    uint4 A[4];
#pragma unroll
    for (int u = 0; u < 4; ++u) A[u] = yb[(size_t)ss[u] * 16 + l];
#pragma unroll
    for (int u = 0; u < 4; ++u) {
      float p = fmaxf(BFLO(A[u].x) + d[0], 0.f) * w[0] +
                fmaxf(BFHI(A[u].x) + d[1], 0.f) * w[1] +
                fmaxf(BFLO(A[u].y) + d[2], 0.f) * w[2] +
                fmaxf(BFHI(A[u].y) + d[3], 0.f) * w[3] +
                fmaxf(BFLO(A[u].z) + d[4], 0.f) * w[4] +
                fmaxf(BFHI(A[u].z) + d[5], 0.f) * w[5] +
                fmaxf(BFLO(A[u].w) + d[6], 0.f) * w[6] +
                fmaxf(BFHI(A[u].w) + d[7], 0.f) * w[7];
      p += __shfl_down(p, 8, 16);
      p += __shfl_down(p, 4, 16);
      p += __shfl_down(p, 2, 16);
      p += __shfl_down(p, 1, 16);
      if (l == 0 && qq[u]) out[csr_eid[ii[u]]] = p + ob2;
    }
  }
}

extern "C" void kernel_launch(void* const* d_in, const int* in_sizes, int n_in,
                              void* d_out, int out_size, void* d_ws, size_t ws_size,
                              hipStream_t stream) {
  const float* node_feats = (const float*)d_in[1];
  const int*   src        = (const int*)d_in[2];
  const int*   dst        = (const int*)d_in[3];
  const float* W_nemb     = (const float*)d_in[6];
  const float* b_nemb     = (const float*)d_in[7];
  const float* gnn_W      = (const float*)d_in[8];
  const float* gnn_b      = (const float*)d_in[9];
  const float* out_W1     = (const float*)d_in[10];
  const float* out_b1     = (const float*)d_in[11];
  const float* out_W2     = (const float*)d_in[12];
  const float* out_b2     = (const float*)d_in[13];
  float* out = (float*)d_out;

  size_t off = 0;
  char* base = (char*)d_ws;
  auto alloc = [&](size_t nbytes) -> char* {
    off = (off + 255) & ~(size_t)255;
    char* p = base + off;
    off += nbytes;
    return p;
  };
  int*    bcnt2    = (int*)alloc(2 * NB * 4);
  int*    bofs_d   = (int*)alloc((NB + 1) * 4);
  int*    bofs_s   = (int*)alloc((NB + 1) * 4);
  int*    cur_d    = (int*)alloc(NB * 4);
  int*    cur_s    = (int*)alloc(NB * 4);
  float*  norm_out = (float*)alloc(N_NODES * 4);
  float*  norm_in  = (float*)alloc(N_NODES * 4);
  int*    row_ofs  = (int*)alloc((N_NODES + 1) * 4);
  int*    csr_src  = (int*)alloc((size_t)N_EDGES * 4);
  int*    csr_eid  = (int*)alloc((size_t)N_EDGES * 4);
  float4* agg4     = (float4*)alloc((size_t)N_NODES * 16);
  float*  sno      = (float*)alloc(N_NODES * 4);
  uint4*  h1b      = (uint4*)alloc((size_t)N_NODES * HID * 2);   // bf16 h1*no
  float*  aggbuf   = (float*)alloc((size_t)N_NODES * HID * 4);   // f32 agg
  uint4*  yb       = (uint4*)alloc((size_t)N_NODES * HID * 2);   // bf16 y
  // scatter staging aliases (consumed before their hosts are first written)
  int2*   sdst     = (int2*)aggbuf;  // 6.4 MB, consumed by p4 (aggbuf written later)
  int*    ssrc     = (int*)yb;       // 3.2 MB, consumed by p5 (yb written later)
  int*    bcnt_d   = bcnt2;
  int*    bcnt_s   = bcnt2 + NB;
  (void)ws_size; (void)n_in; (void)in_sizes; (void)out_size;

  hipMemsetAsync(bcnt2, 0, 2 * NB * 4, stream);
  p1_hist_kernel<<<128, 256, 0, stream>>>(src, dst, bcnt_d, bcnt_s);
  p2_scan_kernel<<<1, 256, 0, stream>>>(bcnt_d, bcnt_s, bofs_d, bofs_s, cur_d, cur_s);
  p3_scatter_dst_kernel<<<(N_EDGES + 2047) / 2048, 256, 0, stream>>>(src, dst, cur_d, sdst);
  p3_scatter_src_kernel<<<(N_EDGES + 2047) / 2048, 256, 0, stream>>>(src, cur_s, ssrc);
  p4_csr_kernel<<<NB, 256, 0, stream>>>(sdst, bofs_d, row_ofs, norm_in, csr_src, csr_eid);
  p5_degout_kernel<<<NB, 256, 0, stream>>>(ssrc, bofs_s, norm_out);

  agg4_kernel<<<(N_NODES * 16 + 255) / 256, 256, 0, stream>>>(
      (const float4*)node_feats, norm_out, csr_src, row_ofs, agg4, sno);
  gemm_l1_kernel<<<(N_NODES + 63) / 64, 256, 0, stream>>>(
      agg4, sno, norm_in, norm_out, W_nemb, b_nemb, gnn_W, gnn_b, h1b, N_NODES);

  aggregate_kernel<<<(N_NODES * 64 + 255) / 256, 256, 0, stream>>>(
      h1b, row_ofs, csr_src, norm_in, aggbuf);

  gemm_dual_kernel<<<(N_NODES + 63) / 64, 256, 0, stream>>>(
      aggbuf, gnn_W + (size_t)HID * HID, gnn_b + HID, out_W1, yb, N_NODES);

  edge_out_kernel<<<(N_NODES * 64 + 255) / 256, 256, 0, stream>>>(
      csr_src, csr_eid, row_ofs, yb, out_b1, out_W2, out_b2, out);
}